// Round 2
// baseline (5460.364 us; speedup 1.0000x reference)
//
#include <hip/hip_runtime.h>
#include <stdint.h>

// Problem constants
#define T_   512
#define B_   64
#define DIN  1024
#define HID  512
#define G3   1536     // 3*HID
#define NC   3072     // both dirs of gates
#define MROWS 32768   // T_*B_
#define MEMB 16       // members per chain (per direction)

typedef __bf16 bf16;
typedef __bf16 bf16x8 __attribute__((ext_vector_type(8)));
typedef float  f32x4  __attribute__((ext_vector_type(4)));

#define GLOBAL_AS __attribute__((address_space(1)))
#define LDS_AS    __attribute__((address_space(3)))

__device__ __forceinline__ uint16_t f2bf_bits(float x){
  union{float f; uint32_t u;} v; v.f = x;
  uint32_t u = v.u;
  u += 0x7FFFu + ((u >> 16) & 1u);   // round-to-nearest-even
  return (uint16_t)(u >> 16);
}
__device__ __forceinline__ float bf2f_bits(uint16_t h){
  union{uint32_t u; float f;} v; v.u = ((uint32_t)h) << 16;
  return v.f;
}

// ---------------------------------------------------------------- converts
__global__ void k_conv_emb(const float* __restrict__ src, uint16_t* __restrict__ dst, long n8){
  long i = (long)blockIdx.x*blockDim.x + threadIdx.x;
  if(i >= n8) return;
  const float4* s = (const float4*)src;
  float4 a = s[i*2], b = s[i*2+1];
  uint32_t p0 = (uint32_t)f2bf_bits(a.x) | ((uint32_t)f2bf_bits(a.y) << 16);
  uint32_t p1 = (uint32_t)f2bf_bits(a.z) | ((uint32_t)f2bf_bits(a.w) << 16);
  uint32_t p2 = (uint32_t)f2bf_bits(b.x) | ((uint32_t)f2bf_bits(b.y) << 16);
  uint32_t p3 = (uint32_t)f2bf_bits(b.z) | ((uint32_t)f2bf_bits(b.w) << 16);
  ((uint4*)dst)[i] = make_uint4(p0,p1,p2,p3);
}

__global__ void k_conv_wcat(const float* __restrict__ wf, const float* __restrict__ wb, uint16_t* __restrict__ dst, int n){
  int i = blockIdx.x*256 + threadIdx.x;
  if(i >= n) return;
  float v = (i < G3*DIN) ? wf[i] : wb[i - G3*DIN];
  dst[i] = f2bf_bits(v);
}

__global__ void k_conv_awt(const float* __restrict__ aw, uint16_t* __restrict__ dst, int n){
  int i = blockIdx.x*256 + threadIdx.x;
  if(i >= n) return;
  int e = i >> 10, d = i & 1023;
  dst[i] = f2bf_bits(aw[d*1024 + e]);   // transpose: awT[e][d]
}

// ---------------------------------------------------------------- GEMM: xp = emb @ Wcat^T + bias  (bf16 out)
__launch_bounds__(256)
__global__ void k_gemm_xp(const uint16_t* __restrict__ A, const uint16_t* __restrict__ Bw,
                          const float* __restrict__ bihf, const float* __restrict__ bihb,
                          uint16_t* __restrict__ C)
{
  __shared__ uint16_t lA[2][128*32];
  __shared__ uint16_t lB[2][128*32];
  const int K = 1024;
  int bn = blockIdx.x, bm = blockIdx.y;
  int tid = threadIdx.x;
  int lane = tid & 63, wid = tid >> 6;
  int wm = wid >> 1, wn = wid & 1;
  int rowBase = bm*128, colBase = bn*128;
  int rg = lane >> 4, rr = lane & 15;

  auto stage = [&](int buf, int kt){
    #pragma unroll
    for(int i=0;i<2;i++){
      int e = (i*256 + tid)*8;
      int r = e >> 5, c = e & 31;
      __builtin_amdgcn_global_load_lds((const GLOBAL_AS void*)(A + (size_t)(rowBase + r)*K + kt*32 + c),
                                       (LDS_AS void*)&lA[buf][e], 16, 0, 0);
    }
    #pragma unroll
    for(int i=0;i<2;i++){
      int e = (i*256 + tid)*8;
      int r = e >> 5, c = e & 31;
      __builtin_amdgcn_global_load_lds((const GLOBAL_AS void*)(Bw + (size_t)(colBase + r)*K + kt*32 + c),
                                       (LDS_AS void*)&lB[buf][e], 16, 0, 0);
    }
  };

  f32x4 acc[4][4];
  #pragma unroll
  for(int mi=0;mi<4;mi++)
    #pragma unroll
    for(int ni=0;ni<4;ni++) acc[mi][ni] = (f32x4){0.f,0.f,0.f,0.f};

  stage(0, 0);
  __syncthreads();
  for(int kt=0; kt<32; kt++){
    int buf = kt & 1;
    if(kt+1 < 32) stage(buf^1, kt+1);
    bf16x8 af[4], bfv[4];
    #pragma unroll
    for(int mi=0;mi<4;mi++)
      af[mi] = *(const bf16x8*)&lA[buf][(wm*64 + mi*16 + rr)*32 + rg*8];
    #pragma unroll
    for(int ni=0;ni<4;ni++)
      bfv[ni] = *(const bf16x8*)&lB[buf][(wn*64 + ni*16 + rr)*32 + rg*8];
    #pragma unroll
    for(int mi=0;mi<4;mi++)
      #pragma unroll
      for(int ni=0;ni<4;ni++)
        acc[mi][ni] = __builtin_amdgcn_mfma_f32_16x16x32_bf16(af[mi], bfv[ni], acc[mi][ni], 0,0,0);
    __syncthreads();
  }

  #pragma unroll
  for(int ni=0;ni<4;ni++){
    int col = colBase + wn*64 + ni*16 + rr;
    float bv = (col < G3) ? bihf[col] : bihb[col - G3];
    #pragma unroll
    for(int mi=0;mi<4;mi++){
      #pragma unroll
      for(int r=0;r<4;r++){
        int row = rowBase + wm*64 + mi*16 + rg*4 + r;
        C[(size_t)row*NC + col] = f2bf_bits(acc[mi][ni][r] + bv);
      }
    }
  }
}

// ---------------------------------------------------------------- GEMM: attention, fused tanh + ctx_w dot
__launch_bounds__(256)
__global__ void k_gemm_att(const uint16_t* __restrict__ A, const uint16_t* __restrict__ Bw,
                           const float* __restrict__ attn_b, const float* __restrict__ ctx_w,
                           float* __restrict__ scores_raw)
{
  __shared__ uint16_t lA[2][128*32];
  __shared__ uint16_t lB[2][128*32];
  const int K = 1024;
  int bn = blockIdx.x, bm = blockIdx.y;
  int tid = threadIdx.x;
  int lane = tid & 63, wid = tid >> 6;
  int wm = wid >> 1, wn = wid & 1;
  int rowBase = bm*128, colBase = bn*128;
  int rg = lane >> 4, rr = lane & 15;

  auto stage = [&](int buf, int kt){
    #pragma unroll
    for(int i=0;i<2;i++){
      int e = (i*256 + tid)*8;
      int r = e >> 5, c = e & 31;
      __builtin_amdgcn_global_load_lds((const GLOBAL_AS void*)(A + (size_t)(rowBase + r)*K + kt*32 + c),
                                       (LDS_AS void*)&lA[buf][e], 16, 0, 0);
    }
    #pragma unroll
    for(int i=0;i<2;i++){
      int e = (i*256 + tid)*8;
      int r = e >> 5, c = e & 31;
      __builtin_amdgcn_global_load_lds((const GLOBAL_AS void*)(Bw + (size_t)(colBase + r)*K + kt*32 + c),
                                       (LDS_AS void*)&lB[buf][e], 16, 0, 0);
    }
  };

  f32x4 acc[4][4];
  #pragma unroll
  for(int mi=0;mi<4;mi++)
    #pragma unroll
    for(int ni=0;ni<4;ni++) acc[mi][ni] = (f32x4){0.f,0.f,0.f,0.f};

  stage(0, 0);
  __syncthreads();
  for(int kt=0; kt<32; kt++){
    int buf = kt & 1;
    if(kt+1 < 32) stage(buf^1, kt+1);
    bf16x8 af[4], bfv[4];
    #pragma unroll
    for(int mi=0;mi<4;mi++)
      af[mi] = *(const bf16x8*)&lA[buf][(wm*64 + mi*16 + rr)*32 + rg*8];
    #pragma unroll
    for(int ni=0;ni<4;ni++)
      bfv[ni] = *(const bf16x8*)&lB[buf][(wn*64 + ni*16 + rr)*32 + rg*8];
    #pragma unroll
    for(int mi=0;mi<4;mi++)
      #pragma unroll
      for(int ni=0;ni<4;ni++)
        acc[mi][ni] = __builtin_amdgcn_mfma_f32_16x16x32_bf16(af[mi], bfv[ni], acc[mi][ni], 0,0,0);
    __syncthreads();
  }

  float ab[4], cw[4];
  #pragma unroll
  for(int ni=0;ni<4;ni++){
    int col = colBase + wn*64 + ni*16 + rr;
    ab[ni] = attn_b[col];
    cw[ni] = ctx_w[col];
  }
  #pragma unroll
  for(int mi=0;mi<4;mi++){
    #pragma unroll
    for(int r=0;r<4;r++){
      float part = 0.f;
      #pragma unroll
      for(int ni=0;ni<4;ni++) part += tanhf(acc[mi][ni][r] + ab[ni]) * cw[ni];
      #pragma unroll
      for(int off=1; off<16; off<<=1) part += __shfl_xor(part, off);
      if(rr == 0){
        int row = rowBase + wm*64 + mi*16 + rg*4 + r;
        atomicAdd(&scores_raw[row], part);
      }
    }
  }
}

// ---------------------------------------------------------------- recurrence v2: fence-free LLC sync
// 2 chains (dir) x 16 members; member owns 32 h-cols (96 gh-cols) for ALL 64 batch rows.
// h transport: relaxed agent-scope u64 atomics (cache-bypass to coherence point); no fences.
__launch_bounds__(512, 1)
__global__ void k_recur(const uint16_t* __restrict__ xp,
                        const float* __restrict__ whhf, const float* __restrict__ whhb,
                        const float* __restrict__ bhhf, const float* __restrict__ bhhb,
                        unsigned long long* __restrict__ hpub, unsigned* __restrict__ pctr,
                        uint16_t* __restrict__ f_out)
{
  __shared__ uint16_t wl[96*520];   // w_hh slice bf16, padded stride (row = local gh-col)
  __shared__ float    ghl[96*65];   // gh exchange [col][row], stride 65
  __shared__ float    bhl[96];

  int bid = blockIdx.x;
  int dir = bid & 1;
  int member = bid >> 1;        // 0..15
  int jb = member * 32;
  int tid = threadIdx.x;
  int lane = tid & 63, wid = tid >> 6;   // 8 waves
  int rg = lane >> 4, rr = lane & 15;
  int rg4 = wid >> 1;           // batch row-group 0..3
  int chh = wid & 1;            // col half 0..1

  const float* whh = dir ? whhb : whhf;
  const float* bhh = dir ? bhhb : bhhf;

  // stage weights: local gh-row (g*32+j) <-> global gh-row (g*512 + jb + j)
  for(int i = tid; i < 96*512; i += 512){
    int row = i >> 9, k = i & 511;
    int g = row >> 5, j = row & 31;
    wl[row*520 + k] = f2bf_bits(whh[(size_t)(g*512 + jb + j)*512 + k]);
  }
  if(tid < 96){ int g = tid >> 5, j = tid & 31; bhl[tid] = bhh[g*512 + jb + j]; }
  __syncthreads();

  // gate ownership: thread -> (batch row m, 4 cols c0..c0+3)
  int m_own = tid >> 3;
  int c0 = (tid & 7) * 4;
  float hreg[4] = {0.f, 0.f, 0.f, 0.f};

  unsigned* pc = pctr + dir*512;

  for(int t = 0; t < 512; t++){
    int trow = dir ? (511 - t) : t;

    // xp prefetch (plain loads of immutable data; issued before the poll)
    size_t xbase = (size_t)(trow*64 + m_own)*NC + dir*G3 + jb + c0;
    uint2 xw0 = *(const uint2*)(xp + xbase);
    uint2 xw1 = *(const uint2*)(xp + xbase + 512);
    uint2 xw2 = *(const uint2*)(xp + xbase + 1024);

    if(t > 0){
      if(tid == 0){
        while(__hip_atomic_load(&pc[t-1], __ATOMIC_RELAXED, __HIP_MEMORY_SCOPE_AGENT) < (unsigned)MEMB){}
      }
      __syncthreads();   // bar(a): h[t-1] complete at coherence point

      const unsigned long long* hsrc = hpub + (size_t)(dir*2 + ((t-1)&1))*8192;
      int arow = rg4*16 + rr;
      bf16x8 afr[16];
      #pragma unroll
      for(int ks = 0; ks < 16; ks++){
        unsigned long long lo = __hip_atomic_load(&hsrc[arow*128 + ks*8 + rg*2],     __ATOMIC_RELAXED, __HIP_MEMORY_SCOPE_AGENT);
        unsigned long long hi = __hip_atomic_load(&hsrc[arow*128 + ks*8 + rg*2 + 1], __ATOMIC_RELAXED, __HIP_MEMORY_SCOPE_AGENT);
        union{ unsigned long long q[2]; bf16x8 v; } u;
        u.q[0] = lo; u.q[1] = hi;
        afr[ks] = u.v;
      }
      f32x4 acc0 = (f32x4){0,0,0,0}, acc1 = (f32x4){0,0,0,0}, acc2 = (f32x4){0,0,0,0};
      #pragma unroll
      for(int ks = 0; ks < 16; ks++){
        bf16x8 b0 = *(const bf16x8*)&wl[(chh*48 +  0 + rr)*520 + ks*32 + rg*8];
        bf16x8 b1 = *(const bf16x8*)&wl[(chh*48 + 16 + rr)*520 + ks*32 + rg*8];
        bf16x8 b2 = *(const bf16x8*)&wl[(chh*48 + 32 + rr)*520 + ks*32 + rg*8];
        acc0 = __builtin_amdgcn_mfma_f32_16x16x32_bf16(afr[ks], b0, acc0, 0,0,0);
        acc1 = __builtin_amdgcn_mfma_f32_16x16x32_bf16(afr[ks], b1, acc1, 0,0,0);
        acc2 = __builtin_amdgcn_mfma_f32_16x16x32_bf16(afr[ks], b2, acc2, 0,0,0);
      }
      int rbase = rg4*16 + rg*4;
      #pragma unroll
      for(int r = 0; r < 4; r++){
        ghl[(chh*48 +  0 + rr)*65 + rbase + r] = acc0[r];
        ghl[(chh*48 + 16 + rr)*65 + rbase + r] = acc1[r];
        ghl[(chh*48 + 32 + rr)*65 + rbase + r] = acc2[r];
      }
    } else {
      int rbase = rg4*16 + rg*4;
      #pragma unroll
      for(int r = 0; r < 4; r++){
        ghl[(chh*48 +  0 + rr)*65 + rbase + r] = 0.f;
        ghl[(chh*48 + 16 + rr)*65 + rbase + r] = 0.f;
        ghl[(chh*48 + 32 + rr)*65 + rbase + r] = 0.f;
      }
    }
    __syncthreads();   // bar(b): gh visible

    // gates for own (m, c0..c0+3)
    uint16_t hb[4];
    {
      uint32_t xr_[2] = {xw0.x, xw0.y}, xz_[2] = {xw1.x, xw1.y}, xn_[2] = {xw2.x, xw2.y};
      #pragma unroll
      for(int jj = 0; jj < 4; jj++){
        int c = c0 + jj;
        float xr = bf2f_bits((uint16_t)(xr_[jj>>1] >> ((jj&1)*16)));
        float xz = bf2f_bits((uint16_t)(xz_[jj>>1] >> ((jj&1)*16)));
        float xn = bf2f_bits((uint16_t)(xn_[jj>>1] >> ((jj&1)*16)));
        float ghr = ghl[(c     )*65 + m_own] + bhl[c];
        float ghz = ghl[(32 + c)*65 + m_own] + bhl[32 + c];
        float ghn = ghl[(64 + c)*65 + m_own] + bhl[64 + c];
        float rv = 1.f/(1.f + __expf(-(xr + ghr)));
        float zv = 1.f/(1.f + __expf(-(xz + ghz)));
        float nv = tanhf(xn + rv*ghn);
        float hnew = (1.f - zv)*nv + zv*hreg[jj];
        hreg[jj] = hnew;
        hb[jj] = f2bf_bits(hnew);
      }
    }
    unsigned long long pk = (unsigned long long)hb[0]
                          | ((unsigned long long)hb[1] << 16)
                          | ((unsigned long long)hb[2] << 32)
                          | ((unsigned long long)hb[3] << 48);
    // publish h (cache-bypass atomic store) + f_out (plain store)
    __hip_atomic_store(&hpub[(size_t)(dir*2 + (t&1))*8192 + (m_own*512 + jb + c0)/4], pk,
                       __ATOMIC_RELAXED, __HIP_MEMORY_SCOPE_AGENT);
    *(unsigned long long*)&f_out[(size_t)(trow*64 + m_own)*1024 + dir*512 + jb + c0] = pk;

    __syncthreads();   // bar(c): drains vmcnt(0) -> all publishes acked
    if(tid == 0)
      __hip_atomic_fetch_add(&pc[t], 1u, __ATOMIC_RELAXED, __HIP_MEMORY_SCOPE_AGENT);
  }
}

// ---------------------------------------------------------------- softmax over T per batch
__global__ void k_softmax(const float* __restrict__ scores_raw, float* __restrict__ wsm){
  __shared__ float sv[512];
  __shared__ float red[8];
  int b = blockIdx.x;
  int tid = threadIdx.x;
  float mymax = -1e30f;
  for(int t = tid; t < 512; t += 256){
    float s = tanhf(scores_raw[t*64 + b]);
    sv[t] = s;
    mymax = fmaxf(mymax, s);
  }
  #pragma unroll
  for(int off=1; off<64; off<<=1) mymax = fmaxf(mymax, __shfl_xor(mymax, off));
  if((tid&63)==0) red[tid>>6] = mymax;
  __syncthreads();
  float bmax = fmaxf(fmaxf(red[0],red[1]), fmaxf(red[2],red[3]));
  __syncthreads();
  float mysum = 0.f;
  for(int t = tid; t < 512; t += 256){
    float e = __expf(sv[t] - bmax);
    sv[t] = e;
    mysum += e;
  }
  #pragma unroll
  for(int off=1; off<64; off<<=1) mysum += __shfl_xor(mysum, off);
  if((tid&63)==0) red[tid>>6] = mysum;
  __syncthreads();
  float inv = 1.f/(red[0]+red[1]+red[2]+red[3]);
  for(int t = tid; t < 512; t += 256) wsm[b*512 + t] = sv[t]*inv;
}

// ---------------------------------------------------------------- ctx[b,d] = sum_t w[b,t] f[t,b,d]
__global__ void k_ctx(const uint16_t* __restrict__ f_out, const float* __restrict__ wsm, float* __restrict__ ctx){
  __shared__ float wloc[512];
  int b = blockIdx.x >> 2, chunk = blockIdx.x & 3;
  int tid = threadIdx.x;
  for(int t = tid; t < 512; t += 256) wloc[t] = wsm[b*512 + t];
  __syncthreads();
  int d = chunk*256 + tid;
  float acc = 0.f;
  #pragma unroll 8
  for(int t = 0; t < 512; t++)
    acc += wloc[t] * bf2f_bits(f_out[(size_t)(t*64 + b)*1024 + d]);
  ctx[b*1024 + d] = acc;
}

// ---------------------------------------------------------------- classifier
__global__ void k_cls1(const float* __restrict__ ctx, const float* __restrict__ w1,
                       const float* __restrict__ b1, float* __restrict__ hid){
  int idx = blockIdx.x*256 + threadIdx.x;   // 32768
  int b = idx >> 9, h = idx & 511;
  float acc = b1[h];
  for(int d = 0; d < 1024; d++) acc += ctx[b*1024 + d] * w1[d*512 + h];
  hid[idx] = fmaxf(acc, 0.f);
}

__global__ void k_cls2(const float* __restrict__ hid, const float* __restrict__ w2,
                       const float* __restrict__ b2, float* __restrict__ out){
  int idx = threadIdx.x;   // 640
  if(idx >= 640) return;
  int b = idx / 10, o = idx % 10;
  float acc = b2[o];
  for(int h = 0; h < 512; h++) acc += hid[b*512 + h] * w2[h*10 + o];
  out[idx] = acc;
}

// ---------------------------------------------------------------- launch
extern "C" void kernel_launch(void* const* d_in, const int* in_sizes, int n_in,
                              void* d_out, int out_size, void* d_ws, size_t ws_size,
                              hipStream_t stream)
{
  const float* emb    = (const float*)d_in[1];
  const float* w_ih_f = (const float*)d_in[2];
  const float* w_hh_f = (const float*)d_in[3];
  const float* b_ih_f = (const float*)d_in[4];
  const float* b_hh_f = (const float*)d_in[5];
  const float* w_ih_b = (const float*)d_in[6];
  const float* w_hh_b = (const float*)d_in[7];
  const float* b_ih_b = (const float*)d_in[8];
  const float* b_hh_b = (const float*)d_in[9];
  const float* attn_w = (const float*)d_in[10];
  const float* attn_b = (const float*)d_in[11];
  const float* ctx_w  = (const float*)d_in[12];
  const float* cls_w1 = (const float*)d_in[13];
  const float* cls_b1 = (const float*)d_in[14];
  const float* cls_w2 = (const float*)d_in[15];
  const float* cls_b2 = (const float*)d_in[16];
  float* out = (float*)d_out;

  char* ws = (char*)d_ws;
  size_t off = 0;
  auto alloc = [&](size_t bytes){ void* p = ws + off; off += (bytes + 255) & ~(size_t)255; return p; };
  uint16_t* femb = (uint16_t*)alloc((size_t)MROWS*DIN*2);      // emb bf16, later overlaid by f_out
  uint16_t* wcat = (uint16_t*)alloc((size_t)NC*DIN*2);
  uint16_t* xp   = (uint16_t*)alloc((size_t)MROWS*NC*2);
  uint16_t* awT  = (uint16_t*)alloc((size_t)1024*1024*2);
  unsigned long long* hpub = (unsigned long long*)alloc((size_t)4*8192*8);  // [dir][par][64][512] bf16
  unsigned* pctr = (unsigned*)alloc(2*512*4);
  float* scraw   = (float*)alloc((size_t)MROWS*4);
  float* wsm     = (float*)alloc((size_t)B_*T_*4);
  float* ctx     = (float*)alloc((size_t)B_*1024*4);
  float* hid     = (float*)alloc((size_t)B_*512*4);

  hipMemsetAsync(pctr, 0, 2*512*4, stream);
  hipMemsetAsync(scraw, 0, (size_t)MROWS*4, stream);

  k_conv_emb<<<16384, 256, 0, stream>>>(emb, femb, (long)MROWS*DIN/8);
  k_conv_wcat<<<12288, 256, 0, stream>>>(w_ih_f, w_ih_b, wcat, NC*DIN);
  k_conv_awt<<<4096, 256, 0, stream>>>(attn_w, awT, 1024*1024);

  k_gemm_xp<<<dim3(24,256), 256, 0, stream>>>(femb, wcat, b_ih_f, b_ih_b, xp);

  k_recur<<<32, 512, 0, stream>>>(xp, w_hh_f, w_hh_b, b_hh_f, b_hh_b, hpub, pctr, femb /* = f_out */);

  k_gemm_att<<<dim3(8,256), 256, 0, stream>>>(femb, awT, attn_b, ctx_w, scraw);
  k_softmax<<<64, 256, 0, stream>>>(scraw, wsm);
  k_ctx<<<256, 256, 0, stream>>>(femb, wsm, ctx);
  k_cls1<<<128, 256, 0, stream>>>(ctx, cls_w1, cls_b1, hid);
  k_cls2<<<1, 640, 0, stream>>>(hid, cls_w2, cls_b2, out);
}